// Round 3
// baseline (456.807 us; speedup 1.0000x reference)
//
#include <hip/hip_runtime.h>
#include <cstdint>

// SiVALinear factorized path, R3:
//  - revert R2's fused-cast staging (it serialized the K-loop: MfmaUtil 24->17.7)
//  - keep split-K=2 on GEMM A (occupancy 2->4 blocks/CU) + fp32 partials + reduce
//  - keep XCD-aware swizzle (FETCH 271->110 MB held)
//  - all GEMM staging is pure global_load_lds width-16 DMA (m97 structure)

#define BM 128
#define BN 128
#define BK 32

typedef __bf16 bf16x8 __attribute__((ext_vector_type(8)));
typedef float f32x4 __attribute__((ext_vector_type(4)));

__device__ __forceinline__ unsigned short f32_to_bf16(float f) {
    union { float f; uint32_t u; } v; v.f = f;
    uint32_t u = v.u;
    u += 0x7FFF + ((u >> 16) & 1);   // RNE
    return (unsigned short)(u >> 16);
}

// ---------- cast fp32 -> bf16, vec4 ----------
__global__ void cast_f32_bf16(const float* __restrict__ src,
                              unsigned short* __restrict__ dst, int n4) {
    int i = blockIdx.x * blockDim.x + threadIdx.x;
    if (i >= n4) return;
    float4 v = ((const float4*)src)[i];
    ushort4 o;
    o.x = f32_to_bf16(v.x); o.y = f32_to_bf16(v.y);
    o.z = f32_to_bf16(v.z); o.w = f32_to_bf16(v.w);
    ((ushort4*)dst)[i] = o;
}

// ---------- build U_cat[o, r] * S[r] -> bf16 [4096 x 1024] row-major ----------
__global__ void build_u(const float* __restrict__ u_t, const float* __restrict__ u_d,
                        const float* __restrict__ s, unsigned short* __restrict__ ub,
                        int n4) {
    int i = blockIdx.x * blockDim.x + threadIdx.x;
    if (i >= n4) return;
    int e = i * 4;
    int o = e >> 10;
    int r = e & 1023;
    float4 u;
    if (r < 64) u = *(const float4*)(u_t + (size_t)o * 64 + r);
    else        u = *(const float4*)(u_d + (size_t)o * 960 + (r - 64));
    float4 sv = *(const float4*)(s + r);
    ushort4 w;
    w.x = f32_to_bf16(u.x * sv.x);
    w.y = f32_to_bf16(u.y * sv.y);
    w.z = f32_to_bf16(u.z * sv.z);
    w.w = f32_to_bf16(u.w * sv.w);
    ((ushort4*)ub)[i] = w;
}

// ---------- async global->LDS, 16B per lane ----------
__device__ __forceinline__ void stage16(const unsigned short* g, unsigned short* l) {
    __builtin_amdgcn_global_load_lds(
        (const __attribute__((address_space(1))) uint32_t*)g,
        (__attribute__((address_space(3))) uint32_t*)l, 16, 0, 0);
}

// ---------- GEMM A (split-K=2): Yp[z][8192,1024] = xb @ Vb^T ----------
// grid (8, 64, 2); swizzle keeps the 8 N-blocks of a row-tile on one XCD.
__global__ __launch_bounds__(256)
void gemm_a(const unsigned short* __restrict__ A, const unsigned short* __restrict__ B,
            float* __restrict__ Yp) {
    __shared__ unsigned short ldsA[BM * BK];
    __shared__ unsigned short ldsB[BN * BK];

    const int tid  = threadIdx.x;
    const int wave = tid >> 6, lane = tid & 63;
    const int wm = wave >> 1, wn = wave & 1;
    const int q = lane >> 4, l16 = lane & 15;

    const int b = blockIdx.x + (blockIdx.y << 3);
    const int c = b & 7;
    const int t = b >> 3;
    const int tx = t & 7;
    const int ty = ((t >> 3) << 3) + c;     // ty ≡ c (mod 8)
    const int m0 = ty * BM, n0 = tx * BN;
    const int kbase = blockIdx.z * 2048;    // split-K half

    f32x4 acc[4][4] = {};

    const int rowc = tid >> 2;
    const int colc = (tid & 3) << 3;
    const unsigned short* gA0 = A + (size_t)(m0 + rowc) * 4096 + kbase + colc;
    const unsigned short* gA1 = gA0 + (size_t)64 * 4096;
    const unsigned short* gB0 = B + (size_t)(n0 + rowc) * 4096 + kbase + colc;
    const unsigned short* gB1 = gB0 + (size_t)64 * 4096;
    unsigned short* lA0 = ldsA + tid * 8;
    unsigned short* lA1 = ldsA + (tid + 256) * 8;
    unsigned short* lB0 = ldsB + tid * 8;
    unsigned short* lB1 = ldsB + (tid + 256) * 8;

    for (int kt = 0; kt < 64; ++kt) {
        const int k0 = kt * BK;
        stage16(gA0 + k0, lA0);
        stage16(gA1 + k0, lA1);
        stage16(gB0 + k0, lB0);
        stage16(gB1 + k0, lB1);
        asm volatile("s_waitcnt vmcnt(0)" ::: "memory");
        __syncthreads();

        bf16x8 af[4], bfr[4];
#pragma unroll
        for (int i = 0; i < 4; ++i) {
            af[i]  = *(const bf16x8*)(ldsA + (wm * 64 + i * 16 + l16) * BK + q * 8);
            bfr[i] = *(const bf16x8*)(ldsB + (wn * 64 + i * 16 + l16) * BK + q * 8);
        }
#pragma unroll
        for (int mt = 0; mt < 4; ++mt)
#pragma unroll
            for (int nt = 0; nt < 4; ++nt)
                acc[mt][nt] = __builtin_amdgcn_mfma_f32_16x16x32_bf16(
                    af[mt], bfr[nt], acc[mt][nt], 0, 0, 0);
        __syncthreads();
    }

    float* out = Yp + (size_t)blockIdx.z * 8192 * 1024;
#pragma unroll
    for (int mt = 0; mt < 4; ++mt)
#pragma unroll
        for (int nt = 0; nt < 4; ++nt) {
            const int col = n0 + wn * 64 + nt * 16 + l16;
            const int rbase = m0 + wm * 64 + mt * 16 + q * 4;
#pragma unroll
            for (int i = 0; i < 4; ++i)
                out[(size_t)(rbase + i) * 1024 + col] = acc[mt][nt][i];
        }
}

// ---------- reduce split-K partials -> bf16 Y ----------
__global__ void reduce_y(const float* __restrict__ p0, const float* __restrict__ p1,
                         unsigned short* __restrict__ y, int n4) {
    int i = blockIdx.x * blockDim.x + threadIdx.x;
    if (i >= n4) return;
    float4 a = ((const float4*)p0)[i];
    float4 b = ((const float4*)p1)[i];
    ushort4 w;
    w.x = f32_to_bf16(a.x + b.x);
    w.y = f32_to_bf16(a.y + b.y);
    w.z = f32_to_bf16(a.z + b.z);
    w.w = f32_to_bf16(a.w + b.w);
    ((ushort4*)y)[i] = w;
}

// ---------- GEMM B: out[8192,4096] = Yb[8192,1024] @ Ub^T + bias ----------
__global__ __launch_bounds__(256)
void gemm_b(const unsigned short* __restrict__ A, const unsigned short* __restrict__ B,
            float* __restrict__ C, const float* __restrict__ bias) {
    __shared__ unsigned short ldsA[BM * BK];
    __shared__ unsigned short ldsB[BN * BK];

    const int tid  = threadIdx.x;
    const int wave = tid >> 6, lane = tid & 63;
    const int wm = wave >> 1, wn = wave & 1;
    const int q = lane >> 4, l16 = lane & 15;

    const int b = blockIdx.x + (blockIdx.y << 5);   // [0,2048)
    const int c = b & 7;
    const int t = b >> 3;                           // [0,256)
    const int tx = t & 31;
    const int ty = ((t >> 5) << 3) + c;
    const int m0 = ty * BM, n0 = tx * BN;

    const int K = 1024, N = 4096;
    f32x4 acc[4][4] = {};

    const int rowc = tid >> 2;
    const int colc = (tid & 3) << 3;
    const unsigned short* gA0 = A + (size_t)(m0 + rowc) * K + colc;
    const unsigned short* gA1 = gA0 + (size_t)64 * K;
    const unsigned short* gB0 = B + (size_t)(n0 + rowc) * K + colc;
    const unsigned short* gB1 = gB0 + (size_t)64 * K;
    unsigned short* lA0 = ldsA + tid * 8;
    unsigned short* lA1 = ldsA + (tid + 256) * 8;
    unsigned short* lB0 = ldsB + tid * 8;
    unsigned short* lB1 = ldsB + (tid + 256) * 8;

    for (int kt = 0; kt < K / BK; ++kt) {
        const int k0 = kt * BK;
        stage16(gA0 + k0, lA0);
        stage16(gA1 + k0, lA1);
        stage16(gB0 + k0, lB0);
        stage16(gB1 + k0, lB1);
        asm volatile("s_waitcnt vmcnt(0)" ::: "memory");
        __syncthreads();

        bf16x8 af[4], bfr[4];
#pragma unroll
        for (int i = 0; i < 4; ++i) {
            af[i]  = *(const bf16x8*)(ldsA + (wm * 64 + i * 16 + l16) * BK + q * 8);
            bfr[i] = *(const bf16x8*)(ldsB + (wn * 64 + i * 16 + l16) * BK + q * 8);
        }
#pragma unroll
        for (int mt = 0; mt < 4; ++mt)
#pragma unroll
            for (int nt = 0; nt < 4; ++nt)
                acc[mt][nt] = __builtin_amdgcn_mfma_f32_16x16x32_bf16(
                    af[mt], bfr[nt], acc[mt][nt], 0, 0, 0);
        __syncthreads();
    }

#pragma unroll
    for (int mt = 0; mt < 4; ++mt)
#pragma unroll
        for (int nt = 0; nt < 4; ++nt) {
            const int col = n0 + wn * 64 + nt * 16 + l16;
            const int rbase = m0 + wm * 64 + mt * 16 + q * 4;
            const float bv = bias[col];
#pragma unroll
            for (int i = 0; i < 4; ++i)
                C[(size_t)(rbase + i) * N + col] = acc[mt][nt][i] + bv;
        }
}

extern "C" void kernel_launch(void* const* d_in, const int* in_sizes, int n_in,
                              void* d_out, int out_size, void* d_ws, size_t ws_size,
                              hipStream_t stream) {
    const float* x    = (const float*)d_in[0];
    const float* u_t  = (const float*)d_in[1];
    const float* u_d  = (const float*)d_in[2];
    const float* s    = (const float*)d_in[3];
    const float* v_t  = (const float*)d_in[4];
    const float* v_d  = (const float*)d_in[5];
    const float* bias = (const float*)d_in[6];
    float* out = (float*)d_out;

    const int M = 8192, IN = 4096, R = 1024, OUT = 4096;

    char* ws = (char*)d_ws;
    float*          Yp = (float*)ws;                                    // 2 x 32 MiB
    unsigned short* xb = (unsigned short*)(ws + (size_t)(64 << 20));    // 64 MiB
    unsigned short* Vb = (unsigned short*)(ws + (size_t)(128 << 20));   //  8 MiB
    unsigned short* Ub = (unsigned short*)(ws + (size_t)(136 << 20));   //  8 MiB
    unsigned short* Yb = (unsigned short*)(ws + (size_t)(144 << 20));   // 16 MiB

    {   // x -> bf16 (streaming)
        int n4 = M * IN / 4;
        cast_f32_bf16<<<(n4 + 255) / 256, 256, 0, stream>>>(x, xb, n4);
    }
    {   // V casts (tiny)
        int n4 = 64 * IN / 4;
        cast_f32_bf16<<<(n4 + 255) / 256, 256, 0, stream>>>(v_t, Vb, n4);
    }
    {
        int n4 = 960 * IN / 4;
        cast_f32_bf16<<<(n4 + 255) / 256, 256, 0, stream>>>(v_d, Vb + 64 * IN, n4);
    }
    {   // U' = U*S -> bf16
        int n4 = OUT * R / 4;
        build_u<<<(n4 + 255) / 256, 256, 0, stream>>>(u_t, u_d, s, Ub, n4);
    }

    // GEMM A: Yp[z] = xb @ Vb^T, split-K=2
    gemm_a<<<dim3(R / BN, M / BM, 2), 256, 0, stream>>>(xb, Vb, Yp);
    // reduce partials -> bf16 Y
    {
        int n4 = M * R / 4;
        reduce_y<<<(n4 + 255) / 256, 256, 0, stream>>>(Yp, Yp + (size_t)M * R, Yb, n4);
    }
    // GEMM B: out = Yb @ Ub^T + bias
    gemm_b<<<dim3(OUT / BN, M / BM), 256, 0, stream>>>(Yb, Ub, out, bias);
}

// Round 5
// 434.122 us; speedup vs baseline: 1.0523x; 1.0523x over previous
//
#include <hip/hip_runtime.h>
#include <cstdint>

// SiVALinear factorized path, R4 (resubmit — R4 bench hit GPUAcquisitionTimeout):
//  - ONE change vs R3: register-budget fix for occupancy.
//    R3 gemm_a = 88 VGPR + 64 AGPR = 152/wave -> 3 waves/SIMD theoretical,
//    measured occupancy 20% (~1.6 blocks/CU) -> K-loop runs at HBM latency
//    (~1090 cyc/iter, unoverlapped). R2's kernel at 64+64=128 regs measured
//    34.5% occupancy. Force 128-reg budget: __launch_bounds__(256, 4)
//    + pointer-increment K-loop (fewer live address regs, less per-iter VALU).
//  - keep: split-K=2, XCD swizzle, pure global_load_lds w=16 staging.

#define BM 128
#define BN 128
#define BK 32

typedef __bf16 bf16x8 __attribute__((ext_vector_type(8)));
typedef float f32x4 __attribute__((ext_vector_type(4)));

__device__ __forceinline__ unsigned short f32_to_bf16(float f) {
    union { float f; uint32_t u; } v; v.f = f;
    uint32_t u = v.u;
    u += 0x7FFF + ((u >> 16) & 1);   // RNE
    return (unsigned short)(u >> 16);
}

// ---------- cast fp32 -> bf16, vec4 ----------
__global__ void cast_f32_bf16(const float* __restrict__ src,
                              unsigned short* __restrict__ dst, int n4) {
    int i = blockIdx.x * blockDim.x + threadIdx.x;
    if (i >= n4) return;
    float4 v = ((const float4*)src)[i];
    ushort4 o;
    o.x = f32_to_bf16(v.x); o.y = f32_to_bf16(v.y);
    o.z = f32_to_bf16(v.z); o.w = f32_to_bf16(v.w);
    ((ushort4*)dst)[i] = o;
}

// ---------- build U_cat[o, r] * S[r] -> bf16 [4096 x 1024] row-major ----------
__global__ void build_u(const float* __restrict__ u_t, const float* __restrict__ u_d,
                        const float* __restrict__ s, unsigned short* __restrict__ ub,
                        int n4) {
    int i = blockIdx.x * blockDim.x + threadIdx.x;
    if (i >= n4) return;
    int e = i * 4;
    int o = e >> 10;
    int r = e & 1023;
    float4 u;
    if (r < 64) u = *(const float4*)(u_t + (size_t)o * 64 + r);
    else        u = *(const float4*)(u_d + (size_t)o * 960 + (r - 64));
    float4 sv = *(const float4*)(s + r);
    ushort4 w;
    w.x = f32_to_bf16(u.x * sv.x);
    w.y = f32_to_bf16(u.y * sv.y);
    w.z = f32_to_bf16(u.z * sv.z);
    w.w = f32_to_bf16(u.w * sv.w);
    ((ushort4*)ub)[i] = w;
}

// ---------- async global->LDS, 16B per lane ----------
__device__ __forceinline__ void stage16(const unsigned short* g, unsigned short* l) {
    __builtin_amdgcn_global_load_lds(
        (const __attribute__((address_space(1))) uint32_t*)g,
        (__attribute__((address_space(3))) uint32_t*)l, 16, 0, 0);
}

// ---------- GEMM A (split-K=2): Yp[z][8192,1024] = xb @ Vb^T ----------
__global__ __launch_bounds__(256, 4)
void gemm_a(const unsigned short* __restrict__ A, const unsigned short* __restrict__ B,
            float* __restrict__ Yp) {
    __shared__ unsigned short ldsA[BM * BK];
    __shared__ unsigned short ldsB[BN * BK];

    const int tid  = threadIdx.x;
    const int wave = tid >> 6, lane = tid & 63;
    const int wm = wave >> 1, wn = wave & 1;
    const int q = lane >> 4, l16 = lane & 15;

    const int b = blockIdx.x + (blockIdx.y << 3);
    const int c = b & 7;
    const int t = b >> 3;
    const int tx = t & 7;
    const int ty = ((t >> 3) << 3) + c;     // ty ≡ c (mod 8): same-row tiles share XCD
    const int m0 = ty * BM, n0 = tx * BN;
    const int kbase = blockIdx.z * 2048;    // split-K half

    f32x4 acc[4][4] = {};

    const int rowc = tid >> 2;
    const int colc = (tid & 3) << 3;
    const unsigned short* pA0 = A + (size_t)(m0 + rowc) * 4096 + kbase + colc;
    const unsigned short* pA1 = pA0 + (size_t)64 * 4096;
    const unsigned short* pB0 = B + (size_t)(n0 + rowc) * 4096 + kbase + colc;
    const unsigned short* pB1 = pB0 + (size_t)64 * 4096;
    unsigned short* lA0 = ldsA + tid * 8;
    unsigned short* lA1 = ldsA + (tid + 256) * 8;
    unsigned short* lB0 = ldsB + tid * 8;
    unsigned short* lB1 = ldsB + (tid + 256) * 8;

    // loop-invariant LDS read offsets
    const int raBase = (wm * 64 + l16) * BK + q * 8;
    const int rbBase = (wn * 64 + l16) * BK + q * 8;

    for (int kt = 0; kt < 64; ++kt) {
        stage16(pA0, lA0);
        stage16(pA1, lA1);
        stage16(pB0, lB0);
        stage16(pB1, lB1);
        pA0 += BK; pA1 += BK; pB0 += BK; pB1 += BK;
        asm volatile("s_waitcnt vmcnt(0)" ::: "memory");
        __syncthreads();

        bf16x8 af[4], bfr[4];
#pragma unroll
        for (int i = 0; i < 4; ++i) {
            af[i]  = *(const bf16x8*)(ldsA + raBase + i * (16 * BK));
            bfr[i] = *(const bf16x8*)(ldsB + rbBase + i * (16 * BK));
        }
#pragma unroll
        for (int mt = 0; mt < 4; ++mt)
#pragma unroll
            for (int nt = 0; nt < 4; ++nt)
                acc[mt][nt] = __builtin_amdgcn_mfma_f32_16x16x32_bf16(
                    af[mt], bfr[nt], acc[mt][nt], 0, 0, 0);
        __syncthreads();
    }

    float* out = Yp + (size_t)blockIdx.z * 8192 * 1024;
#pragma unroll
    for (int mt = 0; mt < 4; ++mt)
#pragma unroll
        for (int nt = 0; nt < 4; ++nt) {
            const int col = n0 + wn * 64 + nt * 16 + l16;
            const int rbase = m0 + wm * 64 + mt * 16 + q * 4;
#pragma unroll
            for (int i = 0; i < 4; ++i)
                out[(size_t)(rbase + i) * 1024 + col] = acc[mt][nt][i];
        }
}

// ---------- reduce split-K partials -> bf16 Y ----------
__global__ void reduce_y(const float* __restrict__ p0, const float* __restrict__ p1,
                         unsigned short* __restrict__ y, int n4) {
    int i = blockIdx.x * blockDim.x + threadIdx.x;
    if (i >= n4) return;
    float4 a = ((const float4*)p0)[i];
    float4 b = ((const float4*)p1)[i];
    ushort4 w;
    w.x = f32_to_bf16(a.x + b.x);
    w.y = f32_to_bf16(a.y + b.y);
    w.z = f32_to_bf16(a.z + b.z);
    w.w = f32_to_bf16(a.w + b.w);
    ((ushort4*)y)[i] = w;
}

// ---------- GEMM B: out[8192,4096] = Yb[8192,1024] @ Ub^T + bias ----------
__global__ __launch_bounds__(256, 4)
void gemm_b(const unsigned short* __restrict__ A, const unsigned short* __restrict__ B,
            float* __restrict__ C, const float* __restrict__ bias) {
    __shared__ unsigned short ldsA[BM * BK];
    __shared__ unsigned short ldsB[BN * BK];

    const int tid  = threadIdx.x;
    const int wave = tid >> 6, lane = tid & 63;
    const int wm = wave >> 1, wn = wave & 1;
    const int q = lane >> 4, l16 = lane & 15;

    const int b = blockIdx.x + (blockIdx.y << 5);   // [0,2048)
    const int c = b & 7;
    const int t = b >> 3;                           // [0,256)
    const int tx = t & 31;
    const int ty = ((t >> 5) << 3) + c;
    const int m0 = ty * BM, n0 = tx * BN;

    const int K = 1024, N = 4096;
    f32x4 acc[4][4] = {};

    const int rowc = tid >> 2;
    const int colc = (tid & 3) << 3;
    const unsigned short* pA0 = A + (size_t)(m0 + rowc) * K + colc;
    const unsigned short* pA1 = pA0 + (size_t)64 * K;
    const unsigned short* pB0 = B + (size_t)(n0 + rowc) * K + colc;
    const unsigned short* pB1 = pB0 + (size_t)64 * K;
    unsigned short* lA0 = ldsA + tid * 8;
    unsigned short* lA1 = ldsA + (tid + 256) * 8;
    unsigned short* lB0 = ldsB + tid * 8;
    unsigned short* lB1 = ldsB + (tid + 256) * 8;

    const int raBase = (wm * 64 + l16) * BK + q * 8;
    const int rbBase = (wn * 64 + l16) * BK + q * 8;

    for (int kt = 0; kt < K / BK; ++kt) {
        stage16(pA0, lA0);
        stage16(pA1, lA1);
        stage16(pB0, lB0);
        stage16(pB1, lB1);
        pA0 += BK; pA1 += BK; pB0 += BK; pB1 += BK;
        asm volatile("s_waitcnt vmcnt(0)" ::: "memory");
        __syncthreads();

        bf16x8 af[4], bfr[4];
#pragma unroll
        for (int i = 0; i < 4; ++i) {
            af[i]  = *(const bf16x8*)(ldsA + raBase + i * (16 * BK));
            bfr[i] = *(const bf16x8*)(ldsB + rbBase + i * (16 * BK));
        }
#pragma unroll
        for (int mt = 0; mt < 4; ++mt)
#pragma unroll
            for (int nt = 0; nt < 4; ++nt)
                acc[mt][nt] = __builtin_amdgcn_mfma_f32_16x16x32_bf16(
                    af[mt], bfr[nt], acc[mt][nt], 0, 0, 0);
        __syncthreads();
    }

#pragma unroll
    for (int mt = 0; mt < 4; ++mt)
#pragma unroll
        for (int nt = 0; nt < 4; ++nt) {
            const int col = n0 + wn * 64 + nt * 16 + l16;
            const int rbase = m0 + wm * 64 + mt * 16 + q * 4;
            const float bv = bias[col];
#pragma unroll
            for (int i = 0; i < 4; ++i)
                C[(size_t)(rbase + i) * N + col] = acc[mt][nt][i] + bv;
        }
}

extern "C" void kernel_launch(void* const* d_in, const int* in_sizes, int n_in,
                              void* d_out, int out_size, void* d_ws, size_t ws_size,
                              hipStream_t stream) {
    const float* x    = (const float*)d_in[0];
    const float* u_t  = (const float*)d_in[1];
    const float* u_d  = (const float*)d_in[2];
    const float* s    = (const float*)d_in[3];
    const float* v_t  = (const float*)d_in[4];
    const float* v_d  = (const float*)d_in[5];
    const float* bias = (const float*)d_in[6];
    float* out = (float*)d_out;

    const int M = 8192, IN = 4096, R = 1024, OUT = 4096;

    char* ws = (char*)d_ws;
    float*          Yp = (float*)ws;                                    // 2 x 32 MiB
    unsigned short* xb = (unsigned short*)(ws + (size_t)(64 << 20));    // 64 MiB
    unsigned short* Vb = (unsigned short*)(ws + (size_t)(128 << 20));   //  8 MiB
    unsigned short* Ub = (unsigned short*)(ws + (size_t)(136 << 20));   //  8 MiB
    unsigned short* Yb = (unsigned short*)(ws + (size_t)(144 << 20));   // 16 MiB

    {   // x -> bf16 (streaming)
        int n4 = M * IN / 4;
        cast_f32_bf16<<<(n4 + 255) / 256, 256, 0, stream>>>(x, xb, n4);
    }
    {   // V casts (tiny)
        int n4 = 64 * IN / 4;
        cast_f32_bf16<<<(n4 + 255) / 256, 256, 0, stream>>>(v_t, Vb, n4);
    }
    {
        int n4 = 960 * IN / 4;
        cast_f32_bf16<<<(n4 + 255) / 256, 256, 0, stream>>>(v_d, Vb + 64 * IN, n4);
    }
    {   // U' = U*S -> bf16
        int n4 = OUT * R / 4;
        build_u<<<(n4 + 255) / 256, 256, 0, stream>>>(u_t, u_d, s, Ub, n4);
    }

    // GEMM A: Yp[z] = xb @ Vb^T, split-K=2
    gemm_a<<<dim3(R / BN, M / BM, 2), 256, 0, stream>>>(xb, Vb, Yp);
    // reduce partials -> bf16 Y
    {
        int n4 = M * R / 4;
        reduce_y<<<(n4 + 255) / 256, 256, 0, stream>>>(Yp, Yp + (size_t)M * R, Yb, n4);
    }
    // GEMM B: out = Yb @ Ub^T + bias
    gemm_b<<<dim3(OUT / BN, M / BM), 256, 0, stream>>>(Yb, Ub, out, bias);
}